// Round 5
// baseline (250.939 us; speedup 1.0000x reference)
//
#include <hip/hip_runtime.h>
#include <hip/hip_bf16.h>
#include <hip/hip_cooperative_groups.h>

namespace cg = cooperative_groups;

// B=2, S=1024, E=512, H=2048, P=128, W=257
#define S_LEN 1024
#define E_DIM 512
#define H_DIM 2048
#define EXTA 1296              // 128 front pad + 1024 + 128 back pad + 16 zeros
#define BS_ROWS 2048

typedef __attribute__((ext_vector_type(8))) short bf16x8;
typedef __attribute__((ext_vector_type(4))) float f32x4;

__device__ inline ushort f2bf(float x) {
  union { float f; unsigned u; } c; c.f = x;
  unsigned u = c.u;
  u += 0x7fffu + ((u >> 16) & 1u);   // RNE
  return (ushort)(u >> 16);
}

__device__ inline void gload16(ushort* dst, const ushort* src) {
  __builtin_amdgcn_global_load_lds(
      (const __attribute__((address_space(1))) void*)src,
      (__attribute__((address_space(3))) void*)dst, 16, 0, 0);
}

struct Params {
  const float *x, *bq, *bk, *bv, *b1, *b2, *ln1w, *ln1b, *ln2w, *ln2b;
  const float *wq, *wk, *wv, *w1, *w2;
  float *x_pe, *x1, *ff2, *out;
  ushort *xpebf, *wqkvT, *w1T, *w2T, *q_bf, *k_bf, *v_t, *x1bf, *ff1_bf;
};

union SMem {
  struct { ushort As[128 * 64]; ushort Bs[128 * 64]; } g;                      // 32 KB
  struct {
    float e[16][292];
    ushort p[16][296];
    float inv[16];
    float redS[8][16];
    float redQ[8][16];
    float mu[16];
    float rs[16];
  } a;                                                                          // ~29 KB
  struct { float t[2][32][33]; } tr;                                            // 8.5 KB
};

// ---- shared MFMA GEMM tile: 128x128, K=512 (8 steps of 64), 8 waves (2x4), 64x32/wave ----
// OUT: 1 = bf16+bias+relu; 2 = QKV routing; 3 = fp32 partial at zoff
template <int OUT>
__device__ __forceinline__ void gemm_tile(ushort* As, ushort* Bs,
                                          const ushort* __restrict__ A,
                                          const ushort* __restrict__ Bt,
                                          int row0, int col0, int koff,
                                          int ldaA, int ldaB, int N,
                                          const float* bias, const float* bias2,
                                          const float* bias3, void* Cout,
                                          ushort* q_out, ushort* k_out, ushort* v_out,
                                          size_t zoff) {
  const int tid = threadIdx.x;
  const int lane = tid & 63;
  const int w = tid >> 6;            // 0..7
  const int wr = w >> 2, wc = w & 3; // 2 x 4 waves
  const int l15 = lane & 15, lhi = lane >> 4;
  f32x4 acc[4][2] = {};

  for (int k0 = 0; k0 < 512; k0 += 64) {
#pragma unroll
    for (int it = 0; it < 2; ++it) {
      int u = it * 512 + tid;
      int r = u >> 3;
      int c16 = (u & 7) ^ (r & 7);
      gload16(&As[u * 8], &A[(size_t)(row0 + r) * ldaA + koff + k0 + c16 * 8]);
    }
#pragma unroll
    for (int it = 0; it < 2; ++it) {
      int u = it * 512 + tid;
      int r = u >> 3;
      int c16 = (u & 7) ^ (r & 7);
      gload16(&Bs[u * 8], &Bt[(size_t)(col0 + r) * ldaB + koff + k0 + c16 * 8]);
    }
    __syncthreads();
#pragma unroll
    for (int kk = 0; kk < 2; ++kk) {
      bf16x8 af[4], bfv[2];
#pragma unroll
      for (int mi = 0; mi < 4; ++mi) {
        int r = wr * 64 + mi * 16 + l15;
        int c16 = (kk * 4 + lhi) ^ (r & 7);
        af[mi] = *(const bf16x8*)&As[r * 64 + c16 * 8];
      }
#pragma unroll
      for (int ni = 0; ni < 2; ++ni) {
        int r = wc * 32 + ni * 16 + l15;
        int c16 = (kk * 4 + lhi) ^ (r & 7);
        bfv[ni] = *(const bf16x8*)&Bs[r * 64 + c16 * 8];
      }
#pragma unroll
      for (int mi = 0; mi < 4; ++mi)
#pragma unroll
        for (int ni = 0; ni < 2; ++ni)
          acc[mi][ni] = __builtin_amdgcn_mfma_f32_16x16x32_bf16(af[mi], bfv[ni], acc[mi][ni], 0, 0, 0);
    }
    __syncthreads();
  }

#pragma unroll
  for (int mi = 0; mi < 4; ++mi) {
    int mbase = row0 + wr * 64 + mi * 16 + lhi * 4;
#pragma unroll
    for (int ni = 0; ni < 2; ++ni) {
      int n = col0 + wc * 32 + ni * 16 + l15;
      if constexpr (OUT == 1) {
        float b = bias[n];
        ushort* C = (ushort*)Cout;
#pragma unroll
        for (int j = 0; j < 4; ++j)
          C[(size_t)(mbase + j) * N + n] = f2bf(fmaxf(acc[mi][ni][j] + b, 0.f));
      } else if constexpr (OUT == 3) {
        float* C = (float*)Cout + zoff;
#pragma unroll
        for (int j = 0; j < 4; ++j) C[(size_t)(mbase + j) * N + n] = acc[mi][ni][j];
      } else {
        int sect = n >> 9, nn = n & 511;
        float b = sect == 0 ? bias[nn] : (sect == 1 ? bias2[nn] : bias3[nn]);
        int bb = mbase >> 10;
        int s = mbase & 1023;
        if (sect == 0) {
#pragma unroll
          for (int j = 0; j < 4; ++j)
            q_out[(size_t)(mbase + j) * 512 + nn] = f2bf(acc[mi][ni][j] + b);
        } else if (sect == 1) {
#pragma unroll
          for (int j = 0; j < 4; ++j)
            k_out[((size_t)bb * EXTA + 128 + s + j) * 512 + nn] = f2bf(acc[mi][ni][j] + b);
        } else {
          ushort4 pk;
          pk.x = f2bf(acc[mi][ni][0] + b);
          pk.y = f2bf(acc[mi][ni][1] + b);
          pk.z = f2bf(acc[mi][ni][2] + b);
          pk.w = f2bf(acc[mi][ni][3] + b);
          *(ushort4*)&v_out[((size_t)bb * 512 + nn) * EXTA + 128 + s] = pk;
        }
      }
    }
  }
}

__global__ __launch_bounds__(512, 2) void mega_kernel(Params p) {
  cg::grid_group grid = cg::this_grid();
  __shared__ SMem sm;
  const int bid = blockIdx.x;
  const int tid = threadIdx.x;
  const int lane = tid & 63;
  const int w = tid >> 6;
  const int l15 = lane & 15, lhi = lane >> 4;

  // ---------------- phase 0: prep (PE add, pads, weight transposes) ----------------
  {
    const int sub = tid >> 8;
    const int t256 = tid & 255;
    for (int iter = 0; iter < 18; ++iter) {
      int j = iter * 512 + bid * 2 + sub;
      bool isT = (j >= 6272 && j < 9088);
      const float* Wsrc = nullptr; ushort* WT = nullptr; int K = 0, N = 0, bx = 0, by = 0;
      if (j < 4096) {
        int idx = j * 256 + t256;
        int e = idx & (E_DIM - 1);
        int s = (idx >> 9) & (S_LEN - 1);
        const float c = -9.210340371976184f / 512.0f;
        float freq = expf((float)(e & ~1) * c);
        float ang = (float)s * freq;
        float pe = (e & 1) ? cosf(ang) : sinf(ang);
        float v = p.x[idx] + pe;
        p.x_pe[idx] = v;
        p.xpebf[idx] = f2bf(v);
      } else if (j < 6272) {
        int pp = (j - 4096) * 256 + t256;
        int t2 = pp / (2 * 272 * 512);
        int r2 = pp % (2 * 272 * 512);
        int b = r2 / (272 * 512);
        int r3 = r2 % (272 * 512);
        if (t2 == 0) {
          int rr = r3 >> 9, e = r3 & 511;
          int row = rr < 128 ? rr : 1024 + rr;
          float v = rr < 256 ? p.bk[e] : 0.f;
          p.k_bf[((size_t)b * EXTA + row) * 512 + e] = f2bf(v);
        } else {
          int n = r3 / 272, jj = r3 % 272;
          int col = jj < 128 ? jj : 1024 + jj;
          float v = jj < 256 ? p.bv[n] : 0.f;
          p.v_t[((size_t)b * 512 + n) * EXTA + col] = f2bf(v);
        }
      } else if (isT) {
        int tile = j - 6272;
        if (tile < 768) {
          K = 512; N = 512;
          int sect = tile >> 8, tt = tile & 255;
          Wsrc = sect == 0 ? p.wq : (sect == 1 ? p.wk : p.wv);
          WT = p.wqkvT + (size_t)sect * 512 * 512;
          bx = tt & 15; by = tt >> 4;
        } else if (tile < 1792) {
          K = 512; N = 2048; Wsrc = p.w1; WT = p.w1T;
          int tt = tile - 768; bx = tt & 63; by = tt >> 6;
        } else {
          K = 2048; N = 512; Wsrc = p.w2; WT = p.w2T;
          int tt = tile - 1792; bx = tt & 15; by = tt >> 4;
        }
        int lx = t256 & 31, ly = t256 >> 5;
        int n0 = bx * 32, k0 = by * 32;
#pragma unroll
        for (int r = 0; r < 4; ++r)
          sm.tr.t[sub][ly + r * 8][lx] = Wsrc[(size_t)(k0 + ly + r * 8) * N + n0 + lx];
      }
      __syncthreads();
      if (isT) {
        int lx = t256 & 31, ly = t256 >> 5;
        int n0 = bx * 32, k0 = by * 32;
#pragma unroll
        for (int r = 0; r < 4; ++r)
          WT[(size_t)(n0 + ly + r * 8) * K + k0 + lx] = f2bf(sm.tr.t[sub][lx][ly + r * 8]);
      }
      __syncthreads();
    }
  }
  grid.sync();

  // ---------------- phase 1: QKV GEMM (M=2048, N=1536) ----------------
  if (bid < 192) {
    int trow = bid / 12, tcol = bid % 12;
    gemm_tile<2>(sm.g.As, sm.g.Bs, p.xpebf, p.wqkvT, trow * 128, tcol * 128, 0,
                 512, 512, 1536, p.bq, p.bk, p.bv, nullptr, p.q_bf, p.k_bf, p.v_t, 0);
  }
  grid.sync();

  // ---------------- phase 2: banded attention + LN1 (128 tiles) ----------------
  if (bid < 128) {
    const int b = bid >> 6;
    const int s0 = (bid & 63) * 16;
    const int base0 = b * 1024 + s0;

    const ushort* qrow = p.q_bf + (size_t)(base0 + l15) * 512 + lhi * 8;
    bf16x8 qf[16];
#pragma unroll
    for (int ks = 0; ks < 16; ++ks) qf[ks] = *(const bf16x8*)(qrow + ks * 32);

    const float scale = 0.044194173824159216f;  // 1/sqrt(512)
    const ushort* kbase = p.k_bf + (size_t)b * EXTA * 512 + (size_t)(s0 + l15) * 512 + lhi * 8;

    for (int jt = w; jt < 18; jt += 8) {
      f32x4 acc = {};
      const ushort* kp = kbase + (size_t)jt * 16 * 512;
#pragma unroll
      for (int ks = 0; ks < 16; ++ks) {
        bf16x8 kf = *(const bf16x8*)(kp + ks * 32);
        acc = __builtin_amdgcn_mfma_f32_16x16x32_bf16(qf[ks], kf, acc, 0, 0, 0);
      }
      int jc = jt * 16 + l15;
#pragma unroll
      for (int j = 0; j < 4; ++j) {
        int i = lhi * 4 + j;
        bool valid = (jc >= i) && (jc <= i + 256);
        sm.a.e[i][jc] = valid ? acc[j] * scale : -1e30f;
      }
    }
    __syncthreads();

    {
      int r = tid >> 5, c0 = tid & 31;
      float m = -1e30f;
#pragma unroll
      for (int t = 0; t < 9; ++t) m = fmaxf(m, sm.a.e[r][c0 + 32 * t]);
#pragma unroll
      for (int off = 1; off <= 16; off <<= 1) m = fmaxf(m, __shfl_xor(m, off));
      float s = 0.f;
#pragma unroll
      for (int t = 0; t < 9; ++t) {
        float pv = __expf(sm.a.e[r][c0 + 32 * t] - m);
        s += pv;
        sm.a.p[r][c0 + 32 * t] = f2bf(pv);
      }
#pragma unroll
      for (int off = 1; off <= 16; off <<= 1) s += __shfl_xor(s, off);
      if (c0 == 0) sm.a.inv[r] = 1.0f / s;
    }
    __syncthreads();

    bf16x8 pf[9];
#pragma unroll
    for (int ks = 0; ks < 9; ++ks) pf[ks] = *(const bf16x8*)&sm.a.p[l15][ks * 32 + lhi * 8];
    float inv[4];
#pragma unroll
    for (int j = 0; j < 4; ++j) inv[j] = sm.a.inv[lhi * 4 + j];

    const ushort* vbase = p.v_t + (size_t)b * 512 * EXTA + s0 + lhi * 8;
    float val[4][4];
#pragma unroll
    for (int ni = 0; ni < 4; ++ni) {
      int n = w * 64 + ni * 16 + l15;
      f32x4 acc = {};
      const ushort* vp = vbase + (size_t)n * EXTA;
#pragma unroll
      for (int ks = 0; ks < 9; ++ks) {
        bf16x8 vf = *(const bf16x8*)(vp + ks * 32);
        acc = __builtin_amdgcn_mfma_f32_16x16x32_bf16(pf[ks], vf, acc, 0, 0, 0);
      }
#pragma unroll
      for (int j = 0; j < 4; ++j) {
        int r = lhi * 4 + j;
        val[ni][j] = acc[j] * inv[j] + p.x_pe[(size_t)(base0 + r) * 512 + n];
      }
    }

    float S[4], Q[4];
#pragma unroll
    for (int j = 0; j < 4; ++j) {
      S[j] = 0.f; Q[j] = 0.f;
#pragma unroll
      for (int ni = 0; ni < 4; ++ni) { S[j] += val[ni][j]; Q[j] += val[ni][j] * val[ni][j]; }
    }
#pragma unroll
    for (int off = 1; off <= 8; off <<= 1) {
#pragma unroll
      for (int j = 0; j < 4; ++j) {
        S[j] += __shfl_xor(S[j], off);
        Q[j] += __shfl_xor(Q[j], off);
      }
    }
    if (l15 == 0) {
#pragma unroll
      for (int j = 0; j < 4; ++j) { sm.a.redS[w][lhi * 4 + j] = S[j]; sm.a.redQ[w][lhi * 4 + j] = Q[j]; }
    }
    __syncthreads();
    if (tid < 16) {
      float sS = 0.f, sQ = 0.f;
#pragma unroll
      for (int ww = 0; ww < 8; ++ww) { sS += sm.a.redS[ww][tid]; sQ += sm.a.redQ[ww][tid]; }
      float mu = sS * (1.0f / 512.0f);
      float var = sQ * (1.0f / 512.0f) - mu * mu;
      sm.a.mu[tid] = mu;
      sm.a.rs[tid] = rsqrtf(var + 1e-5f);
    }
    __syncthreads();

#pragma unroll
    for (int ni = 0; ni < 4; ++ni) {
      int n = w * 64 + ni * 16 + l15;
      float lw = p.ln1w[n], lb = p.ln1b[n];
#pragma unroll
      for (int j = 0; j < 4; ++j) {
        int r = lhi * 4 + j;
        float o = (val[ni][j] - sm.a.mu[r]) * sm.a.rs[r] * lw + lb;
        p.x1[(size_t)(base0 + r) * 512 + n] = o;
        p.x1bf[(size_t)(base0 + r) * 512 + n] = f2bf(o);
      }
    }
  }
  grid.sync();

  // ---------------- phase 3: FFN1 (M=2048, N=2048, relu, bf16 out) ----------------
  {
    int trow = bid >> 4, tcol = bid & 15;
    gemm_tile<1>(sm.g.As, sm.g.Bs, p.x1bf, p.w1T, trow * 128, tcol * 128, 0,
                 512, 512, 2048, p.b1, nullptr, nullptr, p.ff1_bf, nullptr, nullptr, nullptr, 0);
  }
  grid.sync();

  // ---------------- phase 4: FFN2 split-K x4 (M=2048, N=512, K=2048) ----------------
  {
    int slice = bid >> 6, tt = bid & 63;
    int trow = tt >> 2, tcol = tt & 3;
    gemm_tile<3>(sm.g.As, sm.g.Bs, p.ff1_bf, p.w2T, trow * 128, tcol * 128, slice * 512,
                 2048, 2048, 512, nullptr, nullptr, nullptr, p.ff2, nullptr, nullptr, nullptr,
                 (size_t)slice * BS_ROWS * 512);
  }
  grid.sync();

  // ---------------- phase 5: LN2 ----------------
  {
    int r = bid * 8 + w;
    int c0 = lane * 8;
    float v[8];
    const float* pa = p.ff2 + (size_t)r * 512 + c0;
    {
      const float4* q4 = (const float4*)pa;
      float4 a = q4[0], bq4 = q4[1];
      v[0] = a.x; v[1] = a.y; v[2] = a.z; v[3] = a.w;
      v[4] = bq4.x; v[5] = bq4.y; v[6] = bq4.z; v[7] = bq4.w;
    }
#pragma unroll
    for (int s = 1; s < 4; ++s) {
      const float4* q4 = (const float4*)(pa + (size_t)s * BS_ROWS * 512);
      float4 a = q4[0], bq4 = q4[1];
      v[0] += a.x; v[1] += a.y; v[2] += a.z; v[3] += a.w;
      v[4] += bq4.x; v[5] += bq4.y; v[6] += bq4.z; v[7] += bq4.w;
    }
    {
      const float4* bb = (const float4*)(p.b2 + c0);
      float4 a = bb[0], b4 = bb[1];
      v[0] += a.x; v[1] += a.y; v[2] += a.z; v[3] += a.w;
      v[4] += b4.x; v[5] += b4.y; v[6] += b4.z; v[7] += b4.w;
      const float4* xr = (const float4*)(p.x1 + (size_t)r * 512 + c0);
      float4 c = xr[0], d = xr[1];
      v[0] += c.x; v[1] += c.y; v[2] += c.z; v[3] += c.w;
      v[4] += d.x; v[5] += d.y; v[6] += d.z; v[7] += d.w;
    }
    float S = 0.f, Q = 0.f;
#pragma unroll
    for (int j = 0; j < 8; ++j) { S += v[j]; Q += v[j] * v[j]; }
#pragma unroll
    for (int off = 1; off <= 32; off <<= 1) { S += __shfl_xor(S, off); Q += __shfl_xor(Q, off); }
    float mu = S * (1.0f / 512.0f);
    float var = Q * (1.0f / 512.0f) - mu * mu;
    float rs = rsqrtf(var + 1e-5f);
    const float4* lw4 = (const float4*)(p.ln2w + c0);
    const float4* lb4 = (const float4*)(p.ln2b + c0);
    float4 w0 = lw4[0], w1v = lw4[1], b0 = lb4[0], b1v = lb4[1];
    float ow[8] = {w0.x, w0.y, w0.z, w0.w, w1v.x, w1v.y, w1v.z, w1v.w};
    float ob[8] = {b0.x, b0.y, b0.z, b0.w, b1v.x, b1v.y, b1v.z, b1v.w};
    float4 o0, o1;
    o0.x = (v[0] - mu) * rs * ow[0] + ob[0];
    o0.y = (v[1] - mu) * rs * ow[1] + ob[1];
    o0.z = (v[2] - mu) * rs * ow[2] + ob[2];
    o0.w = (v[3] - mu) * rs * ow[3] + ob[3];
    o1.x = (v[4] - mu) * rs * ow[4] + ob[4];
    o1.y = (v[5] - mu) * rs * ow[5] + ob[5];
    o1.z = (v[6] - mu) * rs * ow[6] + ob[6];
    o1.w = (v[7] - mu) * rs * ow[7] + ob[7];
    float* op = p.out + (size_t)r * 512 + c0;
    ((float4*)op)[0] = o0;
    ((float4*)op)[1] = o1;
  }
}

// ---------------- launch ----------------
extern "C" void kernel_launch(void* const* d_in, const int* in_sizes, int n_in,
                              void* d_out, int out_size, void* d_ws, size_t ws_size,
                              hipStream_t stream) {
  char* W = (char*)d_ws;
  Params p;
  p.x    = (const float*)d_in[0];
  p.wq   = (const float*)d_in[1];
  p.bq   = (const float*)d_in[2];
  p.wk   = (const float*)d_in[3];
  p.bk   = (const float*)d_in[4];
  p.wv   = (const float*)d_in[5];
  p.bv   = (const float*)d_in[6];
  p.w1   = (const float*)d_in[7];
  p.b1   = (const float*)d_in[8];
  p.w2   = (const float*)d_in[9];
  p.b2   = (const float*)d_in[10];
  p.ln1w = (const float*)d_in[11];
  p.ln1b = (const float*)d_in[12];
  p.ln2w = (const float*)d_in[13];
  p.ln2b = (const float*)d_in[14];

  p.x_pe   = (float*)(W);                      // 4MB  @0
  p.xpebf  = (ushort*)(W + (4u  << 20));       // 2MB  @4
  p.wqkvT  = (ushort*)(W + (6u  << 20));       // 1.5MB@6
  p.w1T    = (ushort*)(W + (8u  << 20));       // 2MB  @8
  p.w2T    = (ushort*)(W + (10u << 20));       // 2MB  @10
  p.q_bf   = (ushort*)(W + (12u << 20));       // 2MB  @12
  p.k_bf   = (ushort*)(W + (14u << 20));       // 2.6MB@14
  p.v_t    = (ushort*)(W + (17u << 20));       // 2.6MB@17
  p.x1     = (float*)(W + (20u << 20));        // 4MB  @20
  p.x1bf   = (ushort*)(W + (24u << 20));       // 2MB  @24
  p.ff1_bf = (ushort*)(W + (26u << 20));       // 8MB  @26
  p.ff2    = (float*)(W + (34u << 20));        // 4x4MB@34 (split-K partials)
  p.out    = (float*)d_out;

  void* args[] = {&p};
  hipLaunchCooperativeKernel((void*)mega_kernel, dim3(256), dim3(512), args, 0, stream);
}

// Round 6
// 86.176 us; speedup vs baseline: 2.9119x; 2.9119x over previous
//
#include <hip/hip_runtime.h>
#include <hip/hip_bf16.h>

// B=2, S=1024, E=512, H=2048, P=128, W=257
#define S_LEN 1024
#define E_DIM 512
#define H_DIM 2048
#define EXTA 1296              // 128 front pad + 1024 + 128 back pad + 16 zeros (band tiles)
#define BS_ROWS 2048

typedef __attribute__((ext_vector_type(8))) short bf16x8;
typedef __attribute__((ext_vector_type(4))) float f32x4;

__device__ inline ushort f2bf(float x) {
  union { float f; unsigned u; } c; c.f = x;
  unsigned u = c.u;
  u += 0x7fffu + ((u >> 16) & 1u);   // RNE
  return (ushort)(u >> 16);
}

__device__ inline void gload16(ushort* dst, const ushort* src) {
  __builtin_amdgcn_global_load_lds(
      (const __attribute__((address_space(1))) void*)src,
      (__attribute__((address_space(3))) void*)dst, 16, 0, 0);
}

// ---------------- prep: PE add (both batches per thread), pad fill, weight transposes ----------------
// blocks [0,2048): PE; [2048,4224): pads; [4224,7040): transposes
__global__ __launch_bounds__(256) void prep_kernel(const float* __restrict__ x,
                                                   const float* __restrict__ bk,
                                                   const float* __restrict__ bv,
                                                   const float* __restrict__ wq,
                                                   const float* __restrict__ wk,
                                                   const float* __restrict__ wv,
                                                   const float* __restrict__ w1,
                                                   const float* __restrict__ w2,
                                                   float* __restrict__ xpe,
                                                   ushort* __restrict__ xpe_bf,
                                                   ushort* __restrict__ k_bf,
                                                   ushort* __restrict__ v_t,
                                                   ushort* __restrict__ wqkvT,
                                                   ushort* __restrict__ w1T,
                                                   ushort* __restrict__ w2T) {
  __shared__ float t[32][33];
  const int blk = blockIdx.x;
  if (blk < 2048) {
    int idx = blk * 256 + threadIdx.x;   // 1024*512 (batch 0 index)
    int e = idx & (E_DIM - 1);
    int s = idx >> 9;
    const float c = -9.210340371976184f / 512.0f;  // -ln(10000)/E
    float freq = expf((float)(e & ~1) * c);
    float ang = (float)s * freq;
    float pe = (e & 1) ? cosf(ang) : sinf(ang);
    float v0 = x[idx] + pe;
    float v1 = x[idx + S_LEN * E_DIM] + pe;
    xpe[idx] = v0;
    xpe[idx + S_LEN * E_DIM] = v1;
    xpe_bf[idx] = f2bf(v0);
    xpe_bf[idx + S_LEN * E_DIM] = f2bf(v1);
  } else if (blk < 4224) {
    int p = (blk - 2048) * 256 + threadIdx.x;  // 2 tensors * 2 batch * 272 * 512
    int t2 = p / (2 * 272 * 512);
    int r2 = p % (2 * 272 * 512);
    int b = r2 / (272 * 512);
    int r3 = r2 % (272 * 512);
    if (t2 == 0) {
      int rr = r3 >> 9, e = r3 & 511;
      int row = rr < 128 ? rr : 1024 + rr;   // front 0..127, back 1152..1279, zeros 1280..1295
      float v = rr < 256 ? bk[e] : 0.f;
      k_bf[((size_t)b * EXTA + row) * 512 + e] = f2bf(v);
    } else {
      int n = r3 / 272, jj = r3 % 272;
      int j = jj < 128 ? jj : 1024 + jj;
      float v = jj < 256 ? bv[n] : 0.f;
      v_t[((size_t)b * 512 + n) * EXTA + j] = f2bf(v);
    }
  } else {
    const int tile = blk - 4224;           // 0..2815
    const float* W; ushort* WT; int K, N, bx, by;
    if (tile < 768) {
      K = 512; N = 512;
      int sect = tile >> 8, tt = tile & 255;
      W = sect == 0 ? wq : (sect == 1 ? wk : wv);
      WT = wqkvT + (size_t)sect * 512 * 512;
      bx = tt & 15; by = tt >> 4;
    } else if (tile < 1792) {
      K = 512; N = 2048; W = w1; WT = w1T;
      int tt = tile - 768; bx = tt & 63; by = tt >> 6;
    } else {
      K = 2048; N = 512; W = w2; WT = w2T;
      int tt = tile - 1792; bx = tt & 15; by = tt >> 4;
    }
    int lx = threadIdx.x & 31, ly = threadIdx.x >> 5;  // 32 x 8
    int n0 = bx * 32, k0 = by * 32;
#pragma unroll
    for (int r = 0; r < 4; ++r)
      t[ly + r * 8][lx] = W[(size_t)(k0 + ly + r * 8) * N + n0 + lx];
    __syncthreads();
#pragma unroll
    for (int r = 0; r < 4; ++r)
      WT[(size_t)(n0 + ly + r * 8) * K + k0 + lx] = f2bf(t[lx][ly + r * 8]);
  }
}

// ---------------- MFMA GEMM (m97 geometry): 128x128 tile, 4 waves, 64x64/wave ----------------
// OUT: 1 = bf16+bias+relu; 2 = QKV routing; 3 = fp32 partial (split-K, no bias)
template <int OUT>
__global__ __launch_bounds__(256) void mfma_gemm(const ushort* __restrict__ A,
                                                 const ushort* __restrict__ Bt,
                                                 const float* __restrict__ bias,
                                                 const float* __restrict__ bias2,
                                                 const float* __restrict__ bias3,
                                                 void* __restrict__ Cout,
                                                 ushort* __restrict__ q_out,
                                                 ushort* __restrict__ k_out,
                                                 ushort* __restrict__ v_out,
                                                 int M, int N, int K, int LDA) {
  __shared__ ushort As[128 * 64];
  __shared__ ushort Bs[128 * 64];
  const int tid = threadIdx.x;
  const int lane = tid & 63;
  const int w = tid >> 6;            // 0..3
  const int wr = w >> 1, wc = w & 1; // 2x2 waves, each 64x64
  const int l15 = lane & 15, lhi = lane >> 4;
  const int col0 = blockIdx.x * 128, row0 = blockIdx.y * 128;
  const int koff = blockIdx.z * K;

  f32x4 acc[4][4] = {};

  for (int k0 = 0; k0 < K; k0 += 64) {
#pragma unroll
    for (int it = 0; it < 4; ++it) {
      int u = it * 256 + tid;        // 0..1023
      int r = u >> 3;                // 0..127
      int c16 = (u & 7) ^ (r & 7);
      gload16(&As[u * 8], &A[(size_t)(row0 + r) * LDA + koff + k0 + c16 * 8]);
    }
#pragma unroll
    for (int it = 0; it < 4; ++it) {
      int u = it * 256 + tid;
      int r = u >> 3;
      int c16 = (u & 7) ^ (r & 7);
      gload16(&Bs[u * 8], &Bt[(size_t)(col0 + r) * LDA + koff + k0 + c16 * 8]);
    }
    __syncthreads();
#pragma unroll
    for (int kk = 0; kk < 2; ++kk) {
      bf16x8 af[4], bfv[4];
#pragma unroll
      for (int mi = 0; mi < 4; ++mi) {
        int r = wr * 64 + mi * 16 + l15;
        int c16 = (kk * 4 + lhi) ^ (r & 7);
        af[mi] = *(const bf16x8*)&As[r * 64 + c16 * 8];
      }
#pragma unroll
      for (int ni = 0; ni < 4; ++ni) {
        int r = wc * 64 + ni * 16 + l15;
        int c16 = (kk * 4 + lhi) ^ (r & 7);
        bfv[ni] = *(const bf16x8*)&Bs[r * 64 + c16 * 8];
      }
#pragma unroll
      for (int mi = 0; mi < 4; ++mi)
#pragma unroll
        for (int ni = 0; ni < 4; ++ni)
          acc[mi][ni] = __builtin_amdgcn_mfma_f32_16x16x32_bf16(af[mi], bfv[ni], acc[mi][ni], 0, 0, 0);
    }
    __syncthreads();
  }

#pragma unroll
  for (int mi = 0; mi < 4; ++mi) {
    int mbase = row0 + wr * 64 + mi * 16 + lhi * 4;
#pragma unroll
    for (int ni = 0; ni < 4; ++ni) {
      int n = col0 + wc * 64 + ni * 16 + l15;
      if constexpr (OUT == 1) {
        float b = bias[n];
        ushort* C = (ushort*)Cout;
#pragma unroll
        for (int j = 0; j < 4; ++j)
          C[(size_t)(mbase + j) * N + n] = f2bf(fmaxf(acc[mi][ni][j] + b, 0.f));
      } else if constexpr (OUT == 3) {
        float* C = (float*)Cout + (size_t)blockIdx.z * M * N;
#pragma unroll
        for (int j = 0; j < 4; ++j) C[(size_t)(mbase + j) * N + n] = acc[mi][ni][j];
      } else {
        int sect = n >> 9, nn = n & 511;
        float b = sect == 0 ? bias[nn] : (sect == 1 ? bias2[nn] : bias3[nn]);
        int bb = mbase >> 10;
        int s = mbase & 1023;
        if (sect == 0) {
#pragma unroll
          for (int j = 0; j < 4; ++j)
            q_out[(size_t)(mbase + j) * 512 + nn] = f2bf(acc[mi][ni][j] + b);
        } else if (sect == 1) {
#pragma unroll
          for (int j = 0; j < 4; ++j)
            k_out[((size_t)bb * EXTA + 128 + s + j) * 512 + nn] = f2bf(acc[mi][ni][j] + b);
        } else {
          ushort4 pk;
          pk.x = f2bf(acc[mi][ni][0] + b);
          pk.y = f2bf(acc[mi][ni][1] + b);
          pk.z = f2bf(acc[mi][ni][2] + b);
          pk.w = f2bf(acc[mi][ni][3] + b);
          *(ushort4*)&v_out[((size_t)bb * 512 + nn) * EXTA + 128 + s] = pk;
        }
      }
    }
  }
}

// ---------------- banded MFMA attention + fused residual LayerNorm1 ----------------
__global__ __launch_bounds__(512) void attn_ln1(const ushort* __restrict__ qb,
                                                const ushort* __restrict__ kb,
                                                const ushort* __restrict__ vt,
                                                const float* __restrict__ x_pe,
                                                const float* __restrict__ ln1w,
                                                const float* __restrict__ ln1b,
                                                float* __restrict__ x1,
                                                ushort* __restrict__ x1bf) {
  __shared__ float e_s[16][292];
  __shared__ ushort p_s[16][296];
  __shared__ float inv_s[16];
  __shared__ float redS[8][16];
  __shared__ float redQ[8][16];
  __shared__ float mu_s[16], rs_s[16];
  const int tid = threadIdx.x;
  const int lane = tid & 63;
  const int w = tid >> 6;          // 0..7
  const int l15 = lane & 15, lhi = lane >> 4;
  const int tile = blockIdx.x;     // 0..127
  const int b = tile >> 6;
  const int s0 = (tile & 63) * 16;
  const int base0 = b * 1024 + s0;

  const ushort* qrow = qb + (size_t)(base0 + l15) * 512 + lhi * 8;
  bf16x8 qf[16];
#pragma unroll
  for (int ks = 0; ks < 16; ++ks) qf[ks] = *(const bf16x8*)(qrow + ks * 32);

  const float scale = 0.044194173824159216f;  // 1/sqrt(512)
  const ushort* kbase = kb + (size_t)b * EXTA * 512 + (size_t)(s0 + l15) * 512 + lhi * 8;

  // energy: wave w -> j-tiles {w, w+8, w+16}
  for (int jt = w; jt < 18; jt += 8) {
    f32x4 acc = {};
    const ushort* kp = kbase + (size_t)jt * 16 * 512;
#pragma unroll
    for (int ks = 0; ks < 16; ++ks) {
      bf16x8 kf = *(const bf16x8*)(kp + ks * 32);
      acc = __builtin_amdgcn_mfma_f32_16x16x32_bf16(qf[ks], kf, acc, 0, 0, 0);
    }
    int jc = jt * 16 + l15;
#pragma unroll
    for (int j = 0; j < 4; ++j) {
      int i = lhi * 4 + j;
      bool valid = (jc >= i) && (jc <= i + 256);
      e_s[i][jc] = valid ? acc[j] * scale : -1e30f;
    }
  }
  __syncthreads();

  // softmax: row r = tid>>5, 32 lanes per row over 288 cols
  {
    int r = tid >> 5, c0 = tid & 31;
    float m = -1e30f;
#pragma unroll
    for (int t = 0; t < 9; ++t) m = fmaxf(m, e_s[r][c0 + 32 * t]);
#pragma unroll
    for (int off = 1; off <= 16; off <<= 1) m = fmaxf(m, __shfl_xor(m, off));
    float s = 0.f;
#pragma unroll
    for (int t = 0; t < 9; ++t) {
      float p = __expf(e_s[r][c0 + 32 * t] - m);
      s += p;
      p_s[r][c0 + 32 * t] = f2bf(p);
    }
#pragma unroll
    for (int off = 1; off <= 16; off <<= 1) s += __shfl_xor(s, off);
    if (c0 == 0) inv_s[r] = 1.0f / s;
  }
  __syncthreads();

  // PV: wave w -> n-tiles w*4 .. w*4+3; keep results in regs for LN
  bf16x8 pf[9];
#pragma unroll
  for (int ks = 0; ks < 9; ++ks) pf[ks] = *(const bf16x8*)&p_s[l15][ks * 32 + lhi * 8];
  float inv[4];
#pragma unroll
  for (int j = 0; j < 4; ++j) inv[j] = inv_s[lhi * 4 + j];

  const ushort* vbase = vt + (size_t)b * 512 * EXTA + s0 + lhi * 8;
  float val[4][4];  // [ni][j]
#pragma unroll
  for (int ni = 0; ni < 4; ++ni) {
    int n = w * 64 + ni * 16 + l15;
    f32x4 acc = {};
    const ushort* vp = vbase + (size_t)n * EXTA;
#pragma unroll
    for (int ks = 0; ks < 9; ++ks) {
      bf16x8 vf = *(const bf16x8*)(vp + ks * 32);
      acc = __builtin_amdgcn_mfma_f32_16x16x32_bf16(pf[ks], vf, acc, 0, 0, 0);
    }
#pragma unroll
    for (int j = 0; j < 4; ++j) {
      int r = lhi * 4 + j;
      val[ni][j] = acc[j] * inv[j] + x_pe[(size_t)(base0 + r) * 512 + n];
    }
  }

  // LN1 stats
  float S[4], Q[4];
#pragma unroll
  for (int j = 0; j < 4; ++j) {
    S[j] = 0.f; Q[j] = 0.f;
#pragma unroll
    for (int ni = 0; ni < 4; ++ni) { S[j] += val[ni][j]; Q[j] += val[ni][j] * val[ni][j]; }
  }
#pragma unroll
  for (int off = 1; off <= 8; off <<= 1) {
#pragma unroll
    for (int j = 0; j < 4; ++j) {
      S[j] += __shfl_xor(S[j], off);
      Q[j] += __shfl_xor(Q[j], off);
    }
  }
  if (l15 == 0) {
#pragma unroll
    for (int j = 0; j < 4; ++j) { redS[w][lhi * 4 + j] = S[j]; redQ[w][lhi * 4 + j] = Q[j]; }
  }
  __syncthreads();
  if (tid < 16) {
    float sS = 0.f, sQ = 0.f;
#pragma unroll
    for (int ww = 0; ww < 8; ++ww) { sS += redS[ww][tid]; sQ += redQ[ww][tid]; }
    float mu = sS * (1.0f / 512.0f);
    float var = sQ * (1.0f / 512.0f) - mu * mu;
    mu_s[tid] = mu;
    rs_s[tid] = rsqrtf(var + 1e-5f);
  }
  __syncthreads();

#pragma unroll
  for (int ni = 0; ni < 4; ++ni) {
    int n = w * 64 + ni * 16 + l15;
    float lw = ln1w[n], lb = ln1b[n];
#pragma unroll
    for (int j = 0; j < 4; ++j) {
      int r = lhi * 4 + j;
      float o = (val[ni][j] - mu_s[r]) * rs_s[r] * lw + lb;
      x1[(size_t)(base0 + r) * 512 + n] = o;
      x1bf[(size_t)(base0 + r) * 512 + n] = f2bf(o);
    }
  }
}

// ---------------- LN2: sum 4 split-K partials + bias + residual, layernorm ----------------
__device__ inline float wave_reduce_sum(float v) {
#pragma unroll
  for (int off = 32; off >= 1; off >>= 1) v += __shfl_xor(v, off);
  return v;
}

__global__ __launch_bounds__(256) void ln2_kernel(const float* __restrict__ parts,
                                                  const float* __restrict__ ab,
                                                  const float* __restrict__ rsd,
                                                  const float* __restrict__ w,
                                                  const float* __restrict__ bias,
                                                  float* __restrict__ out) {
  const int row = blockIdx.x;
  const int tid = threadIdx.x;
  __shared__ float red[8];
  const int e0 = tid * 2;
  const size_t base = (size_t)row * E_DIM + e0;
  const size_t PART = (size_t)BS_ROWS * E_DIM;
  float2 v0 = *(const float2*)(parts + base);
  float2 v1 = *(const float2*)(parts + PART + base);
  float2 v2 = *(const float2*)(parts + 2 * PART + base);
  float2 v3 = *(const float2*)(parts + 3 * PART + base);
  float2 bb = *(const float2*)(ab + e0);
  float2 rv = *(const float2*)(rsd + base);
  float x0 = v0.x + v1.x + v2.x + v3.x + bb.x + rv.x;
  float x1 = v0.y + v1.y + v2.y + v3.y + bb.y + rv.y;

  float sm = wave_reduce_sum(x0 + x1);
  if ((tid & 63) == 0) red[tid >> 6] = sm;
  __syncthreads();
  float mu = (red[0] + red[1] + red[2] + red[3]) * (1.0f / 512.0f);
  float d0 = x0 - mu, d1 = x1 - mu;
  float vs = wave_reduce_sum(d0 * d0 + d1 * d1);
  if ((tid & 63) == 0) red[4 + (tid >> 6)] = vs;
  __syncthreads();
  float var = (red[4] + red[5] + red[6] + red[7]) * (1.0f / 512.0f);
  float inv = rsqrtf(var + 1e-5f);
  float2 wv = *(const float2*)(w + e0);
  float2 bi = *(const float2*)(bias + e0);
  float o0 = d0 * inv * wv.x + bi.x;
  float o1 = d1 * inv * wv.y + bi.y;
  *(float2*)(out + base) = make_float2(o0, o1);
}

// ---------------- launch ----------------
extern "C" void kernel_launch(void* const* d_in, const int* in_sizes, int n_in,
                              void* d_out, int out_size, void* d_ws, size_t ws_size,
                              hipStream_t stream) {
  const float* x    = (const float*)d_in[0];
  const float* wq   = (const float*)d_in[1];
  const float* bq   = (const float*)d_in[2];
  const float* wk   = (const float*)d_in[3];
  const float* bk   = (const float*)d_in[4];
  const float* wv   = (const float*)d_in[5];
  const float* bv   = (const float*)d_in[6];
  const float* w1   = (const float*)d_in[7];
  const float* b1   = (const float*)d_in[8];
  const float* w2   = (const float*)d_in[9];
  const float* b2   = (const float*)d_in[10];
  const float* ln1w = (const float*)d_in[11];
  const float* ln1b = (const float*)d_in[12];
  const float* ln2w = (const float*)d_in[13];
  const float* ln2b = (const float*)d_in[14];

  char* W = (char*)d_ws;
  float*  x_pe   = (float*)(W);                      // 4MB  @0
  ushort* xpebf  = (ushort*)(W + (4u  << 20));       // 2MB  @4
  ushort* wqkvT  = (ushort*)(W + (6u  << 20));       // 1.5MB@6
  ushort* w1T    = (ushort*)(W + (8u  << 20));       // 2MB  @8
  ushort* w2T    = (ushort*)(W + (10u << 20));       // 2MB  @10
  ushort* q_bf   = (ushort*)(W + (12u << 20));       // 2MB  @12
  ushort* k_bf   = (ushort*)(W + (14u << 20));       // 2.6MB@14
  ushort* v_t    = (ushort*)(W + (17u << 20));       // 2.6MB@17
  float*  x1     = (float*)(W + (20u << 20));        // 4MB  @20
  ushort* x1bf   = (ushort*)(W + (24u << 20));       // 2MB  @24
  ushort* ff1_bf = (ushort*)(W + (26u << 20));       // 8MB  @26
  float*  ff2    = (float*)(W + (34u << 20));        // 4x4MB@34 (split-K partials)

  prep_kernel<<<7040, 256, 0, stream>>>(x, bk, bv, wq, wk, wv, w1, w2,
                                        x_pe, xpebf, k_bf, v_t, wqkvT, w1T, w2T);

  // QKV fused: M=2048, N=1536, K=512 (128x128 tiles)
  mfma_gemm<2><<<dim3(12, 16), 256, 0, stream>>>(
      xpebf, wqkvT, bq, bk, bv, nullptr, q_bf, k_bf, v_t, BS_ROWS, 1536, 512, 512);

  attn_ln1<<<128, 512, 0, stream>>>(q_bf, k_bf, v_t, x_pe, ln1w, ln1b, x1, x1bf);

  // FFN1: M=2048, N=2048, K=512, relu, bf16 out
  mfma_gemm<1><<<dim3(16, 16), 256, 0, stream>>>(
      x1bf, w1T, b1, nullptr, nullptr, ff1_bf, nullptr, nullptr, nullptr, BS_ROWS, H_DIM, 512, 512);

  // FFN2: M=2048, N=512, K=2048 split-K x4 -> fp32 partials
  mfma_gemm<3><<<dim3(4, 16, 4), 256, 0, stream>>>(
      ff1_bf, w2T, nullptr, nullptr, nullptr, ff2, nullptr, nullptr, nullptr, BS_ROWS, E_DIM, 512, 2048);

  // LN2: (sum of 4 partials + b2) + x1 residual
  ln2_kernel<<<BS_ROWS, 256, 0, stream>>>(ff2, b2, x1, ln2w, ln2b, (float*)d_out);
}